// Round 1
// baseline (29.369 us; speedup 1.0000x reference)
//
#include <hip/hip_runtime.h>
#include <hip/hip_bf16.h>

// ---------------------------------------------------------------------------
// Kernel 1: compute the two constant 8-vectors (attn_out, ffn_out) on device.
//   attn_vec = <Z_w> of circuit: RX(theta_w) each wire, CNOT ring (0->1..6->7, 7->0)
//   attn_out = attn_vec @ Wc^T + bc
//   ffn_vec[q] = cos^2(ry/2) - sin^2(ry/2)   (RY product state, no entanglement)
//   h = relu(ffn_vec @ W1^T + b1); ffn_out = h @ W2^T + b2
// State layout: flat index i, wire w lives at bit (7-w)  (axis 0 = MSB).
// ---------------------------------------------------------------------------
__global__ void __launch_bounds__(256) qconst_kernel(
    const float* __restrict__ rx, const float* __restrict__ ry,
    const float* __restrict__ Wc, const float* __restrict__ bc,
    const float* __restrict__ W1, const float* __restrict__ b1,
    const float* __restrict__ W2, const float* __restrict__ b2,
    float* __restrict__ ws)  // ws[0..7]=attn_out, ws[8..15]=ffn_out
{
    __shared__ float2 st[256];
    __shared__ float  pr[256];
    __shared__ float  zv[8];
    __shared__ float  hbuf[512];
    const int t = threadIdx.x;

    // |0...0>
    st[t] = make_float2(t == 0 ? 1.0f : 0.0f, 0.0f);
    __syncthreads();

    // RX(theta_w) on wire w: new = c*self + (-i s)*partner  (matrix is symmetric)
    for (int w = 0; w < 8; ++w) {
        const int p = 7 - w;
        const float half = 0.5f * rx[w];
        const float c = cosf(half), s = sinf(half);
        const float2 self = st[t];
        const float2 part = st[t ^ (1 << p)];
        float2 nv;
        nv.x = c * self.x + s * part.y;   // Re(c*a - i*s*b)
        nv.y = c * self.y - s * part.x;   // Im(c*a - i*s*b)
        __syncthreads();
        st[t] = nv;
        __syncthreads();
    }

    // CNOT ring: (0,1),(1,2),...,(6,7),(7,0). If ctrl bit set, take amp with tgt bit flipped.
    for (int k = 0; k < 8; ++k) {
        const int ctrl = (k < 7) ? k : 7;
        const int tgt  = (k < 7) ? k + 1 : 0;
        const int pc = 7 - ctrl, pt = 7 - tgt;
        const float2 v = ((t >> pc) & 1) ? st[t ^ (1 << pt)] : st[t];
        __syncthreads();
        st[t] = v;
        __syncthreads();
    }

    pr[t] = st[t].x * st[t].x + st[t].y * st[t].y;
    __syncthreads();

    // <Z_w> = P(bit=0) - P(bit=1)
    if (t < 8) {
        const int p = 7 - t;
        float z = 0.0f;
        for (int i = 0; i < 256; ++i)
            z += ((i >> p) & 1) ? -pr[i] : pr[i];
        zv[t] = z;
    }
    __syncthreads();

    // attn_out[d] = sum_q zv[q] * Wc[d,q] + bc[d]
    if (t < 8) {
        float acc = bc[t];
        for (int q = 0; q < 8; ++q) acc = fmaf(zv[q], Wc[t * 8 + q], acc);
        ws[t] = acc;
    }

    // ffn_vec (product state): z = c^2 - s^2, same arithmetic path as reference
    float fv[8];
#pragma unroll
    for (int q = 0; q < 8; ++q) {
        const float half = 0.5f * ry[q];
        const float c = cosf(half), s = sinf(half);
        fv[q] = c * c - s * s;
    }
    // h[f] = relu(ffn_vec @ W1[f,:] + b1[f]),  f in [0,512)
    for (int f = t; f < 512; f += 256) {
        float acc = b1[f];
#pragma unroll
        for (int q = 0; q < 8; ++q) acc = fmaf(fv[q], W1[f * 8 + q], acc);
        hbuf[f] = fmaxf(acc, 0.0f);
    }
    __syncthreads();

    // ffn_out[d] = sum_f h[f] * W2[d,f] + b2[d]
    if (t < 8) {
        float acc = b2[t];
        for (int f = 0; f < 512; ++f) acc = fmaf(hbuf[f], W2[t * 512 + f], acc);
        ws[8 + t] = acc;
    }
}

// ---------------------------------------------------------------------------
// Kernel 2: per-row (D=8) fused add + LN1 + add + LN2. One row per thread.
// ---------------------------------------------------------------------------
__global__ void __launch_bounds__(256) fused_ln_kernel(
    const float* __restrict__ x,
    const float* __restrict__ ws,     // [0..7]=attn_out, [8..15]=ffn_out
    const float* __restrict__ ln1w, const float* __restrict__ ln1b,
    const float* __restrict__ ln2w, const float* __restrict__ ln2b,
    float* __restrict__ out, int nrows)
{
    const int row = blockIdx.x * blockDim.x + threadIdx.x;
    if (row >= nrows) return;

    // Uniform constants (scalar loads)
    float att[8], ffn[8], w1[8], b1v[8], w2[8], b2v[8];
#pragma unroll
    for (int j = 0; j < 8; ++j) {
        att[j] = ws[j];
        ffn[j] = ws[8 + j];
        w1[j] = ln1w[j]; b1v[j] = ln1b[j];
        w2[j] = ln2w[j]; b2v[j] = ln2b[j];
    }

    const float4* xp = reinterpret_cast<const float4*>(x + (size_t)row * 8);
    const float4 a = xp[0];
    const float4 b = xp[1];
    float h[8] = {a.x, a.y, a.z, a.w, b.x, b.y, b.z, b.w};

    // h = x + attn_out ; LN1
    float m = 0.0f;
#pragma unroll
    for (int j = 0; j < 8; ++j) { h[j] += att[j]; m += h[j]; }
    m *= 0.125f;
    float v = 0.0f;
#pragma unroll
    for (int j = 0; j < 8; ++j) { const float d = h[j] - m; v = fmaf(d, d, v); }
    v *= 0.125f;
    const float r1 = rsqrtf(v + 1e-5f);

    // g = LN1(h)*w1 + b1 + ffn_out ; LN2
    float g[8];
    float m2 = 0.0f;
#pragma unroll
    for (int j = 0; j < 8; ++j) {
        g[j] = fmaf((h[j] - m) * r1, w1[j], b1v[j]) + ffn[j];
        m2 += g[j];
    }
    m2 *= 0.125f;
    float v2 = 0.0f;
#pragma unroll
    for (int j = 0; j < 8; ++j) { const float d = g[j] - m2; v2 = fmaf(d, d, v2); }
    v2 *= 0.125f;
    const float r2 = rsqrtf(v2 + 1e-5f);

    float o[8];
#pragma unroll
    for (int j = 0; j < 8; ++j)
        o[j] = fmaf((g[j] - m2) * r2, w2[j], b2v[j]);

    float4* op = reinterpret_cast<float4*>(out + (size_t)row * 8);
    op[0] = make_float4(o[0], o[1], o[2], o[3]);
    op[1] = make_float4(o[4], o[5], o[6], o[7]);
}

extern "C" void kernel_launch(void* const* d_in, const int* in_sizes, int n_in,
                              void* d_out, int out_size, void* d_ws, size_t ws_size,
                              hipStream_t stream) {
    const float* x   = (const float*)d_in[0];
    const float* rx  = (const float*)d_in[1];
    const float* ry  = (const float*)d_in[2];
    const float* Wc  = (const float*)d_in[3];
    const float* bc  = (const float*)d_in[4];
    const float* W1  = (const float*)d_in[5];
    const float* b1  = (const float*)d_in[6];
    const float* W2  = (const float*)d_in[7];
    const float* b2  = (const float*)d_in[8];
    const float* ln1w = (const float*)d_in[9];
    const float* ln1b = (const float*)d_in[10];
    const float* ln2w = (const float*)d_in[11];
    const float* ln2b = (const float*)d_in[12];
    float* out = (float*)d_out;
    float* ws  = (float*)d_ws;

    const int nrows = in_sizes[0] / 8;  // B*S

    qconst_kernel<<<1, 256, 0, stream>>>(rx, ry, Wc, bc, W1, b1, W2, b2, ws);

    const int threads = 256;
    const int blocks = (nrows + threads - 1) / threads;
    fused_ln_kernel<<<blocks, threads, 0, stream>>>(x, ws, ln1w, ln1b, ln2w, ln2b, out, nrows);
}

// Round 3
// 17.196 us; speedup vs baseline: 1.7079x; 1.7079x over previous
//
#include <hip/hip_runtime.h>
#include <hip/hip_bf16.h>

typedef float floatx4 __attribute__((ext_vector_type(4)));

// ---------------------------------------------------------------------------
// Kernel 1: constants. attn_out = (<Z> of RX+CNOT-ring circuit) @ Wc^T + bc
//           ffn_out  = relu((c^2-s^2 product state <Z>) @ W1^T + b1) @ W2^T + b2
// State layout: wire w <-> bit (7-w) of flat index (axis 0 = MSB).
// Fully wave-parallel: no serial per-thread loops over >8 elements.
// ---------------------------------------------------------------------------
__global__ void __launch_bounds__(256) qconst_kernel(
    const float* __restrict__ rx, const float* __restrict__ ry,
    const float* __restrict__ Wc, const float* __restrict__ bc,
    const float* __restrict__ W1, const float* __restrict__ b1,
    const float* __restrict__ W2, const float* __restrict__ b2,
    float* __restrict__ ws)  // ws[0..7]=attn_out, ws[8..15]=ffn_out
{
    __shared__ float2 st[256];
    __shared__ float redz[4][8];
    __shared__ float redm[4][8];
    const int t = threadIdx.x;
    const int lane = t & 63;
    const int wv = t >> 6;

    // |0...0>
    st[t] = make_float2(t == 0 ? 1.0f : 0.0f, 0.0f);
    __syncthreads();

    // RX(theta_w) on wire w: new = c*self + (-i s)*partner
    for (int w = 0; w < 8; ++w) {
        const int p = 7 - w;
        const float half = 0.5f * rx[w];
        const float c = cosf(half), s = sinf(half);
        const float2 self = st[t];
        const float2 part = st[t ^ (1 << p)];
        float2 nv;
        nv.x = fmaf(c, self.x, s * part.y);    // Re(c*a - i*s*b)
        nv.y = fmaf(c, self.y, -s * part.x);   // Im(c*a - i*s*b)
        __syncthreads();
        st[t] = nv;
        __syncthreads();
    }

    // All 8 CNOTs composed into one index permutation:
    // final[i] = st[g_0(g_1(...g_7(i)))], applied k = 7 down to 0.
    int j = t;
    for (int k = 7; k >= 0; --k) {
        const int ctrl = (k < 7) ? k : 7;
        const int tgt  = (k < 7) ? k + 1 : 0;
        const int pc = 7 - ctrl, pt = 7 - tgt;
        if ((j >> pc) & 1) j ^= (1 << pt);
    }
    const float2 amp = st[j];
    const float p = fmaf(amp.x, amp.x, amp.y * amp.y);

    // <Z_w>: 8 simultaneous block reductions (wave shfl + 4-wave LDS combine)
    float zp[8];
#pragma unroll
    for (int w = 0; w < 8; ++w)
        zp[w] = ((t >> (7 - w)) & 1) ? -p : p;
#pragma unroll
    for (int off = 32; off >= 1; off >>= 1)
#pragma unroll
        for (int w = 0; w < 8; ++w)
            zp[w] += __shfl_down(zp[w], off);
    if (lane == 0)
#pragma unroll
        for (int w = 0; w < 8; ++w) redz[wv][w] = zp[w];

    // ffn_vec (product state): z_q = c^2 - s^2
    float fv[8];
#pragma unroll
    for (int q = 0; q < 8; ++q) {
        const float half = 0.5f * ry[q];
        const float c = cosf(half), s = sinf(half);
        fv[q] = c * c - s * s;
    }

    // MLP: each thread owns f = t and f = t+256; 8 partial output accumulators
    float acc[8] = {0, 0, 0, 0, 0, 0, 0, 0};
#pragma unroll
    for (int rep = 0; rep < 2; ++rep) {
        const int f = t + rep * 256;
        float hv = b1[f];
#pragma unroll
        for (int q = 0; q < 8; ++q) hv = fmaf(fv[q], W1[f * 8 + q], hv);
        hv = fmaxf(hv, 0.0f);
#pragma unroll
        for (int d = 0; d < 8; ++d) acc[d] = fmaf(hv, W2[d * 512 + f], acc[d]);
    }
#pragma unroll
    for (int off = 32; off >= 1; off >>= 1)
#pragma unroll
        for (int d = 0; d < 8; ++d)
            acc[d] += __shfl_down(acc[d], off);
    if (lane == 0)
#pragma unroll
        for (int d = 0; d < 8; ++d) redm[wv][d] = acc[d];
    __syncthreads();

    if (t < 8) {
        // attn_out[t] = sum_q zv[q] * Wc[t,q] + bc[t]
        float a = bc[t];
#pragma unroll
        for (int q = 0; q < 8; ++q) {
            const float zq = redz[0][q] + redz[1][q] + redz[2][q] + redz[3][q];
            a = fmaf(zq, Wc[t * 8 + q], a);
        }
        ws[t] = a;
        // ffn_out[t]
        ws[8 + t] = redm[0][t] + redm[1][t] + redm[2][t] + redm[3][t] + b2[t];
    }
}

// ---------------------------------------------------------------------------
// Kernel 2: per-row (D=8) fused add + LN1 + add + LN2. One row per thread.
// ---------------------------------------------------------------------------
__global__ void __launch_bounds__(256) fused_ln_kernel(
    const float* __restrict__ x,
    const float* __restrict__ ws,     // [0..7]=attn_out, [8..15]=ffn_out
    const float* __restrict__ ln1w, const float* __restrict__ ln1b,
    const float* __restrict__ ln2w, const float* __restrict__ ln2b,
    float* __restrict__ out, int nrows)
{
    const int row = blockIdx.x * blockDim.x + threadIdx.x;
    if (row >= nrows) return;

    // Uniform constants (scalar loads)
    float att[8], ffn[8], w1[8], b1v[8], w2[8], b2v[8];
#pragma unroll
    for (int j = 0; j < 8; ++j) {
        att[j] = ws[j];
        ffn[j] = ws[8 + j];
        w1[j] = ln1w[j]; b1v[j] = ln1b[j];
        w2[j] = ln2w[j]; b2v[j] = ln2b[j];
    }

    const float4* xp = reinterpret_cast<const float4*>(x + (size_t)row * 8);
    const float4 a = xp[0];
    const float4 b = xp[1];
    float h[8] = {a.x, a.y, a.z, a.w, b.x, b.y, b.z, b.w};

    // h = x + attn_out ; LN1
    float m = 0.0f;
#pragma unroll
    for (int j = 0; j < 8; ++j) { h[j] += att[j]; m += h[j]; }
    m *= 0.125f;
    float v = 0.0f;
#pragma unroll
    for (int j = 0; j < 8; ++j) { const float d = h[j] - m; v = fmaf(d, d, v); }
    v *= 0.125f;
    const float r1 = rsqrtf(v + 1e-5f);

    // g = LN1(h)*w1 + b1 + ffn_out ; LN2
    float g[8];
    float m2 = 0.0f;
#pragma unroll
    for (int j = 0; j < 8; ++j) {
        g[j] = fmaf((h[j] - m) * r1, w1[j], b1v[j]) + ffn[j];
        m2 += g[j];
    }
    m2 *= 0.125f;
    float v2 = 0.0f;
#pragma unroll
    for (int j = 0; j < 8; ++j) { const float d = g[j] - m2; v2 = fmaf(d, d, v2); }
    v2 *= 0.125f;
    const float r2 = rsqrtf(v2 + 1e-5f);

    floatx4 o0, o1;
    o0.x = fmaf((g[0] - m2) * r2, w2[0], b2v[0]);
    o0.y = fmaf((g[1] - m2) * r2, w2[1], b2v[1]);
    o0.z = fmaf((g[2] - m2) * r2, w2[2], b2v[2]);
    o0.w = fmaf((g[3] - m2) * r2, w2[3], b2v[3]);
    o1.x = fmaf((g[4] - m2) * r2, w2[4], b2v[4]);
    o1.y = fmaf((g[5] - m2) * r2, w2[5], b2v[5]);
    o1.z = fmaf((g[6] - m2) * r2, w2[6], b2v[6]);
    o1.w = fmaf((g[7] - m2) * r2, w2[7], b2v[7]);

    floatx4* op = reinterpret_cast<floatx4*>(out + (size_t)row * 8);
    __builtin_nontemporal_store(o0, op);
    __builtin_nontemporal_store(o1, op + 1);
}

extern "C" void kernel_launch(void* const* d_in, const int* in_sizes, int n_in,
                              void* d_out, int out_size, void* d_ws, size_t ws_size,
                              hipStream_t stream) {
    const float* x   = (const float*)d_in[0];
    const float* rx  = (const float*)d_in[1];
    const float* ry  = (const float*)d_in[2];
    const float* Wc  = (const float*)d_in[3];
    const float* bc  = (const float*)d_in[4];
    const float* W1  = (const float*)d_in[5];
    const float* b1  = (const float*)d_in[6];
    const float* W2  = (const float*)d_in[7];
    const float* b2  = (const float*)d_in[8];
    const float* ln1w = (const float*)d_in[9];
    const float* ln1b = (const float*)d_in[10];
    const float* ln2w = (const float*)d_in[11];
    const float* ln2b = (const float*)d_in[12];
    float* out = (float*)d_out;
    float* ws  = (float*)d_ws;

    const int nrows = in_sizes[0] / 8;  // B*S

    qconst_kernel<<<1, 256, 0, stream>>>(rx, ry, Wc, bc, W1, b1, W2, b2, ws);

    const int threads = 256;
    const int blocks = (nrows + threads - 1) / threads;
    fused_ln_kernel<<<blocks, threads, 0, stream>>>(x, ws, ln1w, ln1b, ln2w, ln2b, out, nrows);
}

// Round 4
// 13.155 us; speedup vs baseline: 2.2325x; 1.3072x over previous
//
#include <hip/hip_runtime.h>
#include <hip/hip_bf16.h>

typedef float floatx4 __attribute__((ext_vector_type(4)));

// ---------------------------------------------------------------------------
// Single fused kernel.
//
// Analytic circuit evaluation (Heisenberg pullback of Z_w through the CNOT
// ring over the RX product state):
//   attn_vec[0]   = prod_{j=1..7} cos(rx[j])
//   attn_vec[k]   = prod_{j=0..k} cos(rx[j]),  k = 1..7
//   ffn_vec[q]    = cos(ry[q])                  (RY product state)
// attn_out = attn_vec @ Wc^T + bc
// ffn_out  = W2 @ relu(W1 @ ffn_vec + b1) + b2   (512-wide MLP, block-parallel)
//
// Every block computes the constants redundantly (W1/W2 reads are L2-hits
// after warmup), then streams 512 rows of x through add+LN1+add+LN2.
// x loads are issued BEFORE the constant prologue so HBM latency hides it.
// ---------------------------------------------------------------------------
__global__ void __launch_bounds__(256) fused_all_kernel(
    const float* __restrict__ x,
    const float* __restrict__ rx, const float* __restrict__ ry,
    const float* __restrict__ Wc, const float* __restrict__ bc,
    const float* __restrict__ W1, const float* __restrict__ b1,
    const float* __restrict__ W2, const float* __restrict__ b2,
    const float* __restrict__ ln1w, const float* __restrict__ ln1b,
    const float* __restrict__ ln2w, const float* __restrict__ ln2b,
    float* __restrict__ out, int nrows)
{
    __shared__ float redm[4][8];
    __shared__ float cvec[16];   // [0..7]=attn_out, [8..15]=ffn_out

    const int t = threadIdx.x;
    const int lane = t & 63;
    const int wv = t >> 6;

    const int rowA = blockIdx.x * 512 + t;
    const int rowB = rowA + 256;
    const bool doA = rowA < nrows;
    const bool doB = rowB < nrows;

    // ---- issue streaming loads early; consumed after the prologue ----
    floatx4 xa0 = {0,0,0,0}, xa1 = {0,0,0,0}, xb0 = {0,0,0,0}, xb1 = {0,0,0,0};
    if (doA) {
        const floatx4* p = reinterpret_cast<const floatx4*>(x + (size_t)rowA * 8);
        xa0 = p[0]; xa1 = p[1];
    }
    if (doB) {
        const floatx4* p = reinterpret_cast<const floatx4*>(x + (size_t)rowB * 8);
        xb0 = p[0]; xb1 = p[1];
    }

    // ---- constant prologue (uniform across threads except MLP split) ----
    float ca[8];
#pragma unroll
    for (int q = 0; q < 8; ++q) ca[q] = cosf(rx[q]);
    float attv[8];
    attv[0] = ca[1] * ca[2] * ca[3] * ca[4] * ca[5] * ca[6] * ca[7];
    {
        float p = ca[0];
#pragma unroll
        for (int k = 1; k < 8; ++k) { p *= ca[k]; attv[k] = p; }
    }

    float fz[8];
#pragma unroll
    for (int q = 0; q < 8; ++q) fz[q] = cosf(ry[q]);

    // MLP: thread owns hidden units t and t+256
    float acc[8] = {0, 0, 0, 0, 0, 0, 0, 0};
#pragma unroll
    for (int rep = 0; rep < 2; ++rep) {
        const int f = t + rep * 256;
        float hv = b1[f];
#pragma unroll
        for (int q = 0; q < 8; ++q) hv = fmaf(fz[q], W1[f * 8 + q], hv);
        hv = fmaxf(hv, 0.0f);
#pragma unroll
        for (int d = 0; d < 8; ++d) acc[d] = fmaf(hv, W2[d * 512 + f], acc[d]);
    }
#pragma unroll
    for (int off = 32; off >= 1; off >>= 1)
#pragma unroll
        for (int d = 0; d < 8; ++d)
            acc[d] += __shfl_down(acc[d], off);
    if (lane == 0)
#pragma unroll
        for (int d = 0; d < 8; ++d) redm[wv][d] = acc[d];
    __syncthreads();

    if (t < 8) {
        float a = bc[t];
#pragma unroll
        for (int q = 0; q < 8; ++q) a = fmaf(attv[q], Wc[t * 8 + q], a);
        cvec[t] = a;
        cvec[8 + t] = redm[0][t] + redm[1][t] + redm[2][t] + redm[3][t] + b2[t];
    }
    __syncthreads();

    // ---- per-row constants ----
    float att[8], ffn[8], w1[8], b1v[8], w2[8], b2v[8];
#pragma unroll
    for (int j = 0; j < 8; ++j) {
        att[j] = cvec[j];
        ffn[j] = cvec[8 + j];
        w1[j] = ln1w[j]; b1v[j] = ln1b[j];
        w2[j] = ln2w[j]; b2v[j] = ln2b[j];
    }

    // ---- row math: add + LN1 + add + LN2 ----
    auto process = [&](floatx4 v0, floatx4 v1, floatx4& o0, floatx4& o1) {
        float h[8] = {v0.x, v0.y, v0.z, v0.w, v1.x, v1.y, v1.z, v1.w};
        float m = 0.0f;
#pragma unroll
        for (int j = 0; j < 8; ++j) { h[j] += att[j]; m += h[j]; }
        m *= 0.125f;
        float v = 0.0f;
#pragma unroll
        for (int j = 0; j < 8; ++j) { const float d = h[j] - m; v = fmaf(d, d, v); }
        v *= 0.125f;
        const float r1 = rsqrtf(v + 1e-5f);

        float g[8];
        float m2 = 0.0f;
#pragma unroll
        for (int j = 0; j < 8; ++j) {
            g[j] = fmaf((h[j] - m) * r1, w1[j], b1v[j]) + ffn[j];
            m2 += g[j];
        }
        m2 *= 0.125f;
        float v2 = 0.0f;
#pragma unroll
        for (int j = 0; j < 8; ++j) { const float d = g[j] - m2; v2 = fmaf(d, d, v2); }
        v2 *= 0.125f;
        const float r2 = rsqrtf(v2 + 1e-5f);

        o0.x = fmaf((g[0] - m2) * r2, w2[0], b2v[0]);
        o0.y = fmaf((g[1] - m2) * r2, w2[1], b2v[1]);
        o0.z = fmaf((g[2] - m2) * r2, w2[2], b2v[2]);
        o0.w = fmaf((g[3] - m2) * r2, w2[3], b2v[3]);
        o1.x = fmaf((g[4] - m2) * r2, w2[4], b2v[4]);
        o1.y = fmaf((g[5] - m2) * r2, w2[5], b2v[5]);
        o1.z = fmaf((g[6] - m2) * r2, w2[6], b2v[6]);
        o1.w = fmaf((g[7] - m2) * r2, w2[7], b2v[7]);
    };

    if (doA) {
        floatx4 o0, o1;
        process(xa0, xa1, o0, o1);
        floatx4* op = reinterpret_cast<floatx4*>(out + (size_t)rowA * 8);
        __builtin_nontemporal_store(o0, op);
        __builtin_nontemporal_store(o1, op + 1);
    }
    if (doB) {
        floatx4 o0, o1;
        process(xb0, xb1, o0, o1);
        floatx4* op = reinterpret_cast<floatx4*>(out + (size_t)rowB * 8);
        __builtin_nontemporal_store(o0, op);
        __builtin_nontemporal_store(o1, op + 1);
    }
}

extern "C" void kernel_launch(void* const* d_in, const int* in_sizes, int n_in,
                              void* d_out, int out_size, void* d_ws, size_t ws_size,
                              hipStream_t stream) {
    const float* x   = (const float*)d_in[0];
    const float* rx  = (const float*)d_in[1];
    const float* ry  = (const float*)d_in[2];
    const float* Wc  = (const float*)d_in[3];
    const float* bc  = (const float*)d_in[4];
    const float* W1  = (const float*)d_in[5];
    const float* b1  = (const float*)d_in[6];
    const float* W2  = (const float*)d_in[7];
    const float* b2  = (const float*)d_in[8];
    const float* ln1w = (const float*)d_in[9];
    const float* ln1b = (const float*)d_in[10];
    const float* ln2w = (const float*)d_in[11];
    const float* ln2b = (const float*)d_in[12];
    float* out = (float*)d_out;

    const int nrows = in_sizes[0] / 8;   // B*S = 524288
    const int blocks = (nrows + 511) / 512;

    fused_all_kernel<<<blocks, 256, 0, stream>>>(
        x, rx, ry, Wc, bc, W1, b1, W2, b2,
        ln1w, ln1b, ln2w, ln2b, out, nrows);
}